// Round 16
// baseline (208.666 us; speedup 1.0000x reference)
//
#include <hip/hip_runtime.h>
#include <math.h>

#define D 128

typedef __attribute__((ext_vector_type(8))) short short8v;
typedef __attribute__((ext_vector_type(4))) float f32x4;

__device__ __forceinline__ unsigned short f2bf(float x) {
    unsigned int u = __float_as_uint(x);
    unsigned int r = (u + 0x7FFFu + ((u >> 16) & 1u)) >> 16;
    return (unsigned short)r;
}
__device__ __forceinline__ float bf2f(unsigned short b) {
    return __uint_as_float(((unsigned int)b) << 16);
}

// ---------------- prep: wsplit (frag-ordered hi/lo bf16 W) + zero CNT ---------

__global__ void prep_k(const float* __restrict__ Wp, short* __restrict__ BFh,
                       short* __restrict__ BFl, int wtot,
                       int* __restrict__ cnt, int N) {
    int idx = blockIdx.x * blockDim.x + threadIdx.x;
    if (idx < wtot) {
        int i    = idx & 7;
        int lane = (idx >> 3) & 63;
        int ct   = (idx >> 9) & 7;
        int ks   = (idx >> 12) & 3;
        int l    = idx >> 14;
        int k = ks * 32 + (lane >> 4) * 8 + i;
        int n = ct * 16 + (lane & 15);
        float w = Wp[(size_t)l * (D * D) + (size_t)k * D + n];
        unsigned short h = f2bf(w);
        BFh[idx] = (short)h;
        BFl[idx] = (short)f2bf(w - bf2f(h));
    }
    if (idx < N) cnt[idx] = 0;
}

// ---------------- CSR build ----------------

__global__ void rank_k(const int* __restrict__ dst, int E,
                       int* __restrict__ cnt, unsigned short* __restrict__ rank) {
    int e = blockIdx.x * blockDim.x + threadIdx.x;
    if (e < E) rank[e] = (unsigned short)atomicAdd(&cnt[dst[e]], 1);
}

__global__ __launch_bounds__(1024) void scan_a(const int* __restrict__ cnt, int N,
                                               int* __restrict__ part, int* __restrict__ bsum) {
    __shared__ int s[1024];
    int i = blockIdx.x * 1024 + threadIdx.x;
    int v = (i < N) ? cnt[i] : 0;
    s[threadIdx.x] = v;
    __syncthreads();
    for (int off = 1; off < 1024; off <<= 1) {
        int add = (threadIdx.x >= off) ? s[threadIdx.x - off] : 0;
        __syncthreads();
        s[threadIdx.x] += add;
        __syncthreads();
    }
    if (i < N) part[i] = s[threadIdx.x] - v;
    if (threadIdx.x == 1023) bsum[blockIdx.x] = s[1023];
}

// scan_c with fused block-sum prefix (needs N <= 65536: <=64 chunks).
__global__ __launch_bounds__(256) void scan_c(const int* __restrict__ cnt, int* __restrict__ part,
                                              const int* __restrict__ bsum,
                                              float* __restrict__ dinv, int N, int E) {
    __shared__ int s_pref;
    int chunk = blockIdx.x >> 2;
    if (threadIdx.x < 64) {
        int v = (threadIdx.x < chunk) ? bsum[threadIdx.x] : 0;
#pragma unroll
        for (int off = 1; off < 64; off <<= 1) v += __shfl_xor(v, off);
        if (threadIdx.x == 0) s_pref = v;
    }
    __syncthreads();
    int i = blockIdx.x * blockDim.x + threadIdx.x;
    if (i < N) {
        part[i] = part[i] + s_pref;
        dinv[i] = rsqrtf((float)(cnt[i] + 1));
    }
    if (i == 0) part[N] = E;
}

// ---------------- GEMM pieces ------------------------------------------------

__device__ __forceinline__ void load_a_f32(const float* __restrict__ X, int M,
                                           int rowBase, int lane,
                                           short8v ah[4], short8v al[4]) {
    int arow = rowBase + (lane & 15);
    bool aval = arow < M;
    const float* xr = X + (size_t)arow * D + (lane >> 4) * 8;
#pragma unroll
    for (int ks = 0; ks < 4; ++ks) {
        float4 p = make_float4(0.f, 0.f, 0.f, 0.f);
        float4 q = make_float4(0.f, 0.f, 0.f, 0.f);
        if (aval) {
            p = *(const float4*)(xr + ks * 32);
            q = *(const float4*)(xr + ks * 32 + 4);
        }
        float v[8] = {p.x, p.y, p.z, p.w, q.x, q.y, q.z, q.w};
#pragma unroll
        for (int i = 0; i < 8; ++i) {
            unsigned short h = f2bf(v[i]);
            ah[ks][i] = (short)h;
            al[ks][i] = (short)f2bf(v[i] - bf2f(h));
        }
    }
}

// MFMA phase, B from global (used by fillgemm so fill blocks keep occupancy).
__device__ __forceinline__ void mfma_phase_g(short8v ah[4], short8v al[4],
                                             const short* __restrict__ BFh,
                                             const short* __restrict__ BFl,
                                             const float* __restrict__ dinv,
                                             unsigned short* __restrict__ Hb, int M,
                                             int rowBase, int lane) {
    int rb = rowBase + (lane >> 4) * 4;
    float dsc[4];
#pragma unroll
    for (int i = 0; i < 4; ++i) dsc[i] = (rb + i < M) ? dinv[rb + i] : 0.f;

    const short8v* Bh = (const short8v*)BFh;
    const short8v* Bl = (const short8v*)BFl;
#pragma unroll
    for (int ct = 0; ct < 8; ++ct) {
        short8v bh[4], bl[4];
#pragma unroll
        for (int ks = 0; ks < 4; ++ks) {
            bh[ks] = Bh[(ks * 8 + ct) * 64 + lane];
            bl[ks] = Bl[(ks * 8 + ct) * 64 + lane];
        }
        f32x4 acc = {0.f, 0.f, 0.f, 0.f};
#pragma unroll
        for (int ks = 0; ks < 4; ++ks) {
            acc = __builtin_amdgcn_mfma_f32_16x16x32_bf16(ah[ks], bh[ks], acc, 0, 0, 0);
            acc = __builtin_amdgcn_mfma_f32_16x16x32_bf16(al[ks], bh[ks], acc, 0, 0, 0);
            acc = __builtin_amdgcn_mfma_f32_16x16x32_bf16(ah[ks], bl[ks], acc, 0, 0, 0);
        }
        int c = ct * 16 + (lane & 15);
#pragma unroll
        for (int i = 0; i < 4; ++i) {
            int r = rb + i;
            if (r < M) Hb[(size_t)r * D + c] = f2bf(dsc[i] * acc[i]);
        }
    }
}

// MFMA phase, B from LDS (used by gemm2: W staged once per block).
__device__ __forceinline__ void mfma_phase_l(short8v ah[4], short8v al[4],
                                             const uint4* __restrict__ WH,
                                             const uint4* __restrict__ WL,
                                             const float* __restrict__ dinv,
                                             unsigned short* __restrict__ Hb, int M,
                                             int rowBase, int lane) {
    int rb = rowBase + (lane >> 4) * 4;
    float dsc[4];
#pragma unroll
    for (int i = 0; i < 4; ++i) dsc[i] = (rb + i < M) ? dinv[rb + i] : 0.f;

    const short8v* Bh = (const short8v*)WH;
    const short8v* Bl = (const short8v*)WL;
#pragma unroll
    for (int ct = 0; ct < 8; ++ct) {
        short8v bh[4], bl[4];
#pragma unroll
        for (int ks = 0; ks < 4; ++ks) {
            bh[ks] = Bh[(ks * 8 + ct) * 64 + lane];
            bl[ks] = Bl[(ks * 8 + ct) * 64 + lane];
        }
        f32x4 acc = {0.f, 0.f, 0.f, 0.f};
#pragma unroll
        for (int ks = 0; ks < 4; ++ks) {
            acc = __builtin_amdgcn_mfma_f32_16x16x32_bf16(ah[ks], bh[ks], acc, 0, 0, 0);
            acc = __builtin_amdgcn_mfma_f32_16x16x32_bf16(al[ks], bh[ks], acc, 0, 0, 0);
            acc = __builtin_amdgcn_mfma_f32_16x16x32_bf16(ah[ks], bl[ks], acc, 0, 0, 0);
        }
        int c = ct * 16 + (lane & 15);
#pragma unroll
        for (int i = 0; i < 4; ++i) {
            int r = rb + i;
            if (r < M) Hb[(size_t)r * D + c] = f2bf(dsc[i] * acc[i]);
        }
    }
}

__global__ __launch_bounds__(256) void gemm2_k(const unsigned short* __restrict__ XH,
                                               const unsigned short* __restrict__ XL,
                                               const short* __restrict__ BFh,
                                               const short* __restrict__ BFl,
                                               const float* __restrict__ dinv,
                                               unsigned short* __restrict__ Hb, int M) {
    __shared__ uint4 WH[2048];
    __shared__ uint4 WL[2048];
    {
        const uint4* gh = (const uint4*)BFh;
        const uint4* gl = (const uint4*)BFl;
        int t = threadIdx.x;
#pragma unroll
        for (int i = 0; i < 8; ++i) WH[t + i * 256] = gh[t + i * 256];
#pragma unroll
        for (int i = 0; i < 8; ++i) WL[t + i * 256] = gl[t + i * 256];
    }

    int lane = threadIdx.x & 63;
    int rowBase = blockIdx.x * 64 + (threadIdx.x >> 6) * 16;
    int arow = rowBase + (lane & 15);
    bool aval = arow < M;
    const unsigned short* xh = XH + (size_t)arow * D + (lane >> 4) * 8;
    const unsigned short* xl = XL + (size_t)arow * D + (lane >> 4) * 8;

    short8v ah[4], al[4];
#pragma unroll
    for (int ks = 0; ks < 4; ++ks) {
        short8v zh = {0,0,0,0,0,0,0,0};
        short8v zl = {0,0,0,0,0,0,0,0};
        if (aval) {
            zh = *(const short8v*)(xh + ks * 32);
            zl = *(const short8v*)(xl + ks * 32);
        }
        ah[ks] = zh;
        al[ks] = zl;
    }
    __syncthreads();
    mfma_phase_l(ah, al, WH, WL, dinv, Hb, M, rowBase, lane);
}

// fused: blocks [0,gb) run gemm layer-0 (register-B, no LDS); [gb,..) CSR fill.
__global__ __launch_bounds__(256) void fillgemm_k(const float* __restrict__ X,
                                                  const short* __restrict__ BFh,
                                                  const short* __restrict__ BFl,
                                                  const float* __restrict__ dinv,
                                                  unsigned short* __restrict__ Hb, int M, int gb,
                                                  const int* __restrict__ src,
                                                  const int* __restrict__ dst,
                                                  const unsigned short* __restrict__ rank,
                                                  const int* __restrict__ rp, int E,
                                                  unsigned short* __restrict__ ssrc) {
    if ((int)blockIdx.x < gb) {
        int lane = threadIdx.x & 63;
        int rowBase = blockIdx.x * 64 + (threadIdx.x >> 6) * 16;
        short8v ah[4], al[4];
        load_a_f32(X, M, rowBase, lane, ah, al);
        mfma_phase_g(ah, al, BFh, BFl, dinv, Hb, M, rowBase, lane);
    } else {
        int e = (blockIdx.x - gb) * blockDim.x + threadIdx.x;
        if (e < E) {
            int p = rp[dst[e]] + (int)rank[e];
            ssrc[p] = (unsigned short)src[e];
        }
    }
}

// ---------------- sparse aggregation: depth-2 gather pipeline ----------------
// out[n] = b + dinv[n] * ( h'[n] + sum_e h'[ssrc[e]] ).
// v6: two 16-edge groups double-buffered (vA/vB, 32 VGPR) -> 8 KB in flight
// per wave (vs 4 KB). Statically unrolled group chain, budget kept < 64 VGPR
// (r11's depth-3 crossed the 64-VGPR cliff and halved occupancy).
// mode 0: write split bf16 (XH/XL). mode 1: GELU + f32 OUT.

__device__ __forceinline__ float gelu_f(float x) {
    return 0.5f * x * (1.0f + erff(x * 0.70710678118654752f));
}

#define GLOAD(V, C)                                                       \
    _Pragma("unroll") for (int j = 0; j < 4; ++j) {                       \
        int row_ = __shfl(idxv, (C) + 4 * j + grp);                       \
        V[j] = hb4[(size_t)row_ * 16 + sub];                              \
    }

#define GCONS(V, C)                                                       \
    _Pragma("unroll") for (int j = 0; j < 4; ++j) {                       \
        bool ok_ = (base + (C) + 4 * j + grp) < e1;                       \
        unsigned int w_;                                                  \
        w_ = ok_ ? V[j].x : 0u;                                           \
        acc[0] += __uint_as_float(w_ << 16);                              \
        acc[1] += __uint_as_float(w_ & 0xFFFF0000u);                      \
        w_ = ok_ ? V[j].y : 0u;                                           \
        acc[2] += __uint_as_float(w_ << 16);                              \
        acc[3] += __uint_as_float(w_ & 0xFFFF0000u);                      \
        w_ = ok_ ? V[j].z : 0u;                                           \
        acc[4] += __uint_as_float(w_ << 16);                              \
        acc[5] += __uint_as_float(w_ & 0xFFFF0000u);                      \
        w_ = ok_ ? V[j].w : 0u;                                           \
        acc[6] += __uint_as_float(w_ << 16);                              \
        acc[7] += __uint_as_float(w_ & 0xFFFF0000u);                      \
    }

__global__ __launch_bounds__(256) void agg_k(const unsigned short* __restrict__ Hb,
                                             const int* __restrict__ rp,
                                             const unsigned short* __restrict__ ssrc,
                                             const float* __restrict__ dinv,
                                             const float* __restrict__ bias,
                                             float* __restrict__ outF,
                                             unsigned short* __restrict__ outH,
                                             unsigned short* __restrict__ outL,
                                             int N, int mode) {
    int node = blockIdx.x * 4 + (threadIdx.x >> 6);
    int lane = threadIdx.x & 63;
    if (node >= N) return;
    const uint4* __restrict__ hb4 = (const uint4*)Hb;
    int grp = lane >> 4;
    int sub = lane & 15;

    // prefetch self-term early (used only by lanes<16 after the butterfly)
    uint4 sv = make_uint4(0u, 0u, 0u, 0u);
    if (lane < 16) sv = hb4[(size_t)node * 16 + lane];

    float acc[8];
#pragma unroll
    for (int i = 0; i < 8; ++i) acc[i] = 0.f;

    int e0 = rp[node];
    int e1 = rp[node + 1];
    for (int base = e0; base < e1; base += 64) {
        int idxv = 0;
        if (base + lane < e1) idxv = (int)ssrc[base + lane];
        int cnt = e1 - base; if (cnt > 64) cnt = 64;
        uint4 vA[4], vB[4];
        GLOAD(vA, 0);                         // group 0 in flight
        if (cnt > 16) {
            GLOAD(vB, 16);                    // group 1 in flight (8 KB total)
            GCONS(vA, 0);
            if (cnt > 32) {
                GLOAD(vA, 32);                // reuse vA (statically named)
                GCONS(vB, 16);
                if (cnt > 48) {
                    GLOAD(vB, 48);
                    GCONS(vA, 32);
                    GCONS(vB, 48);
                } else {
                    GCONS(vA, 32);
                }
            } else {
                GCONS(vB, 16);
            }
        } else {
            GCONS(vA, 0);
        }
    }
#pragma unroll
    for (int i = 0; i < 8; ++i) {
        acc[i] += __shfl_xor(acc[i], 16);
        acc[i] += __shfl_xor(acc[i], 32);
    }
    if (lane < 16) {
        acc[0] += __uint_as_float(sv.x << 16); acc[1] += __uint_as_float(sv.x & 0xFFFF0000u);
        acc[2] += __uint_as_float(sv.y << 16); acc[3] += __uint_as_float(sv.y & 0xFFFF0000u);
        acc[4] += __uint_as_float(sv.z << 16); acc[5] += __uint_as_float(sv.z & 0xFFFF0000u);
        acc[6] += __uint_as_float(sv.w << 16); acc[7] += __uint_as_float(sv.w & 0xFFFF0000u);
        float dn = dinv[node];
        float4 b0 = ((const float4*)bias)[lane * 2];
        float4 b1 = ((const float4*)bias)[lane * 2 + 1];
        float r[8];
        r[0] = dn * acc[0] + b0.x; r[1] = dn * acc[1] + b0.y;
        r[2] = dn * acc[2] + b0.z; r[3] = dn * acc[3] + b0.w;
        r[4] = dn * acc[4] + b1.x; r[5] = dn * acc[5] + b1.y;
        r[6] = dn * acc[6] + b1.z; r[7] = dn * acc[7] + b1.w;
        if (mode) {
#pragma unroll
            for (int i = 0; i < 8; ++i) r[i] = gelu_f(r[i]);
            float4 o0 = make_float4(r[0], r[1], r[2], r[3]);
            float4 o1 = make_float4(r[4], r[5], r[6], r[7]);
            ((float4*)outF)[(size_t)node * 32 + lane * 2]     = o0;
            ((float4*)outF)[(size_t)node * 32 + lane * 2 + 1] = o1;
        } else {
            unsigned short h[8], lo[8];
#pragma unroll
            for (int i = 0; i < 8; ++i) {
                h[i]  = f2bf(r[i]);
                lo[i] = f2bf(r[i] - bf2f(h[i]));
            }
            uint4 ph, pl;
            ph.x = (unsigned int)h[0]  | ((unsigned int)h[1] << 16);
            ph.y = (unsigned int)h[2]  | ((unsigned int)h[3] << 16);
            ph.z = (unsigned int)h[4]  | ((unsigned int)h[5] << 16);
            ph.w = (unsigned int)h[6]  | ((unsigned int)h[7] << 16);
            pl.x = (unsigned int)lo[0] | ((unsigned int)lo[1] << 16);
            pl.y = (unsigned int)lo[2] | ((unsigned int)lo[3] << 16);
            pl.z = (unsigned int)lo[4] | ((unsigned int)lo[5] << 16);
            pl.w = (unsigned int)lo[6] | ((unsigned int)lo[7] << 16);
            ((uint4*)outH)[(size_t)node * 16 + lane] = ph;
            ((uint4*)outL)[(size_t)node * 16 + lane] = pl;
        }
    }
}

// ---------------- launch ----------------

extern "C" void kernel_launch(void* const* d_in, const int* in_sizes, int n_in,
                              void* d_out, int out_size, void* d_ws, size_t ws_size,
                              hipStream_t stream) {
    const float* X  = (const float*)d_in[0];
    const int*   EI = (const int*)d_in[1];
    const float* Wp = (const float*)d_in[2];
    const float* bp = (const float*)d_in[3];
    float* OUT = (float*)d_out;

    int N = in_sizes[0] / D;
    int E = in_sizes[1] / 2;
    int L = in_sizes[3] / D;   // 3
    const int* src = EI;
    const int* dst = EI + E;

    char* w = (char*)d_ws;
    auto alloc = [&](size_t bytes) {
        char* p = w;
        w += (bytes + 255) & ~(size_t)255;
        return p;
    };
    unsigned short* HB  = (unsigned short*)alloc((size_t)(N + 64) * D * sizeof(unsigned short));
    unsigned short* XH  = (unsigned short*)alloc((size_t)(N + 64) * D * sizeof(unsigned short));
    unsigned short* XL  = (unsigned short*)alloc((size_t)(N + 64) * D * sizeof(unsigned short));
    float* DINV = (float*)alloc((size_t)N * sizeof(float));
    int*   RP   = (int*)alloc((size_t)(N + 1) * sizeof(int));
    int*   CNT  = (int*)alloc((size_t)N * sizeof(int));
    int*   BSUM = (int*)alloc(4096 * sizeof(int));
    unsigned short* RANK = (unsigned short*)alloc((size_t)E * sizeof(unsigned short));
    unsigned short* SSRC = (unsigned short*)alloc(((size_t)E + 64) * sizeof(unsigned short));
    short* BFH  = (short*)alloc((size_t)L * D * D * sizeof(short));
    short* BFL  = (short*)alloc((size_t)L * D * D * sizeof(short));
    (void)ws_size; (void)n_in; (void)out_size;

    int wtot = L * D * D;
    int pb = ((N > wtot ? N : wtot) + 255) / 256;
    prep_k<<<pb, 256, 0, stream>>>(Wp, BFH, BFL, wtot, CNT, N);

    int eb = (E + 255) / 256;
    rank_k<<<eb, 256, 0, stream>>>(dst, E, CNT, RANK);
    int nb = (N + 1023) / 1024;
    scan_a<<<nb, 1024, 0, stream>>>(CNT, N, RP, BSUM);
    scan_c<<<(N + 255) / 256, 256, 0, stream>>>(CNT, RP, BSUM, DINV, N, E);

    int gb = (N + 63) / 64;
    fillgemm_k<<<gb + eb, 256, 0, stream>>>(X, BFH, BFL, DINV, HB, N, gb,
                                            src, dst, RANK, RP, E, SSRC);

    int ab = (N + 3) / 4;
    agg_k<<<ab, 256, 0, stream>>>(HB, RP, SSRC, DINV, bp, nullptr, XH, XL, N, 0);
    gemm2_k<<<gb, 256, 0, stream>>>(XH, XL, BFH + (size_t)1 * D * D, BFL + (size_t)1 * D * D,
                                    DINV, HB, N);
    agg_k<<<ab, 256, 0, stream>>>(HB, RP, SSRC, DINV, bp + D, nullptr, XH, XL, N, 0);
    gemm2_k<<<gb, 256, 0, stream>>>(XH, XL, BFH + (size_t)2 * D * D, BFL + (size_t)2 * D * D,
                                    DINV, HB, N);
    agg_k<<<ab, 256, 0, stream>>>(HB, RP, SSRC, DINV, bp + 2 * D, OUT, nullptr, nullptr, N, 1);
}

// Round 17
// 201.279 us; speedup vs baseline: 1.0367x; 1.0367x over previous
//
#include <hip/hip_runtime.h>
#include <math.h>

#define D 128

typedef __attribute__((ext_vector_type(8))) short short8v;
typedef __attribute__((ext_vector_type(4))) float f32x4;

__device__ __forceinline__ unsigned short f2bf(float x) {
    unsigned int u = __float_as_uint(x);
    unsigned int r = (u + 0x7FFFu + ((u >> 16) & 1u)) >> 16;
    return (unsigned short)r;
}
__device__ __forceinline__ float bf2f(unsigned short b) {
    return __uint_as_float(((unsigned int)b) << 16);
}

// ---------------- prep: wsplit (frag-ordered hi/lo bf16 W) + zero CNT ---------

__global__ void prep_k(const float* __restrict__ Wp, short* __restrict__ BFh,
                       short* __restrict__ BFl, int wtot,
                       int* __restrict__ cnt, int N) {
    int idx = blockIdx.x * blockDim.x + threadIdx.x;
    if (idx < wtot) {
        int i    = idx & 7;
        int lane = (idx >> 3) & 63;
        int ct   = (idx >> 9) & 7;
        int ks   = (idx >> 12) & 3;
        int l    = idx >> 14;
        int k = ks * 32 + (lane >> 4) * 8 + i;
        int n = ct * 16 + (lane & 15);
        float w = Wp[(size_t)l * (D * D) + (size_t)k * D + n];
        unsigned short h = f2bf(w);
        BFh[idx] = (short)h;
        BFl[idx] = (short)f2bf(w - bf2f(h));
    }
    if (idx < N) cnt[idx] = 0;
}

// ---------------- CSR build ----------------

__global__ void rank_k(const int* __restrict__ dst, int E,
                       int* __restrict__ cnt, unsigned short* __restrict__ rank) {
    int e = blockIdx.x * blockDim.x + threadIdx.x;
    if (e < E) rank[e] = (unsigned short)atomicAdd(&cnt[dst[e]], 1);
}

__global__ __launch_bounds__(1024) void scan_a(const int* __restrict__ cnt, int N,
                                               int* __restrict__ part, int* __restrict__ bsum) {
    __shared__ int s[1024];
    int i = blockIdx.x * 1024 + threadIdx.x;
    int v = (i < N) ? cnt[i] : 0;
    s[threadIdx.x] = v;
    __syncthreads();
    for (int off = 1; off < 1024; off <<= 1) {
        int add = (threadIdx.x >= off) ? s[threadIdx.x - off] : 0;
        __syncthreads();
        s[threadIdx.x] += add;
        __syncthreads();
    }
    if (i < N) part[i] = s[threadIdx.x] - v;
    if (threadIdx.x == 1023) bsum[blockIdx.x] = s[1023];
}

// scan_c with fused block-sum prefix (needs N <= 65536: <=64 chunks).
__global__ __launch_bounds__(256) void scan_c(const int* __restrict__ cnt, int* __restrict__ part,
                                              const int* __restrict__ bsum,
                                              float* __restrict__ dinv, int N, int E) {
    __shared__ int s_pref;
    int chunk = blockIdx.x >> 2;
    if (threadIdx.x < 64) {
        int v = (threadIdx.x < chunk) ? bsum[threadIdx.x] : 0;
#pragma unroll
        for (int off = 1; off < 64; off <<= 1) v += __shfl_xor(v, off);
        if (threadIdx.x == 0) s_pref = v;
    }
    __syncthreads();
    int i = blockIdx.x * blockDim.x + threadIdx.x;
    if (i < N) {
        part[i] = part[i] + s_pref;
        dinv[i] = rsqrtf((float)(cnt[i] + 1));
    }
    if (i == 0) part[N] = E;
}

// ---------------- GEMM pieces ------------------------------------------------

__device__ __forceinline__ void load_a_f32(const float* __restrict__ X, int M,
                                           int rowBase, int lane,
                                           short8v ah[4], short8v al[4]) {
    int arow = rowBase + (lane & 15);
    bool aval = arow < M;
    const float* xr = X + (size_t)arow * D + (lane >> 4) * 8;
#pragma unroll
    for (int ks = 0; ks < 4; ++ks) {
        float4 p = make_float4(0.f, 0.f, 0.f, 0.f);
        float4 q = make_float4(0.f, 0.f, 0.f, 0.f);
        if (aval) {
            p = *(const float4*)(xr + ks * 32);
            q = *(const float4*)(xr + ks * 32 + 4);
        }
        float v[8] = {p.x, p.y, p.z, p.w, q.x, q.y, q.z, q.w};
#pragma unroll
        for (int i = 0; i < 8; ++i) {
            unsigned short h = f2bf(v[i]);
            ah[ks][i] = (short)h;
            al[ks][i] = (short)f2bf(v[i] - bf2f(h));
        }
    }
}

// MFMA phase, B from global (used by fillgemm so fill blocks keep occupancy).
__device__ __forceinline__ void mfma_phase_g(short8v ah[4], short8v al[4],
                                             const short* __restrict__ BFh,
                                             const short* __restrict__ BFl,
                                             const float* __restrict__ dinv,
                                             unsigned short* __restrict__ Hb, int M,
                                             int rowBase, int lane) {
    int rb = rowBase + (lane >> 4) * 4;
    float dsc[4];
#pragma unroll
    for (int i = 0; i < 4; ++i) dsc[i] = (rb + i < M) ? dinv[rb + i] : 0.f;

    const short8v* Bh = (const short8v*)BFh;
    const short8v* Bl = (const short8v*)BFl;
#pragma unroll
    for (int ct = 0; ct < 8; ++ct) {
        short8v bh[4], bl[4];
#pragma unroll
        for (int ks = 0; ks < 4; ++ks) {
            bh[ks] = Bh[(ks * 8 + ct) * 64 + lane];
            bl[ks] = Bl[(ks * 8 + ct) * 64 + lane];
        }
        f32x4 acc = {0.f, 0.f, 0.f, 0.f};
#pragma unroll
        for (int ks = 0; ks < 4; ++ks) {
            acc = __builtin_amdgcn_mfma_f32_16x16x32_bf16(ah[ks], bh[ks], acc, 0, 0, 0);
            acc = __builtin_amdgcn_mfma_f32_16x16x32_bf16(al[ks], bh[ks], acc, 0, 0, 0);
            acc = __builtin_amdgcn_mfma_f32_16x16x32_bf16(ah[ks], bl[ks], acc, 0, 0, 0);
        }
        int c = ct * 16 + (lane & 15);
#pragma unroll
        for (int i = 0; i < 4; ++i) {
            int r = rb + i;
            if (r < M) Hb[(size_t)r * D + c] = f2bf(dsc[i] * acc[i]);
        }
    }
}

// MFMA phase, B from LDS (used by gemm2: W staged once per block).
__device__ __forceinline__ void mfma_phase_l(short8v ah[4], short8v al[4],
                                             const uint4* __restrict__ WH,
                                             const uint4* __restrict__ WL,
                                             const float* __restrict__ dinv,
                                             unsigned short* __restrict__ Hb, int M,
                                             int rowBase, int lane) {
    int rb = rowBase + (lane >> 4) * 4;
    float dsc[4];
#pragma unroll
    for (int i = 0; i < 4; ++i) dsc[i] = (rb + i < M) ? dinv[rb + i] : 0.f;

    const short8v* Bh = (const short8v*)WH;
    const short8v* Bl = (const short8v*)WL;
#pragma unroll
    for (int ct = 0; ct < 8; ++ct) {
        short8v bh[4], bl[4];
#pragma unroll
        for (int ks = 0; ks < 4; ++ks) {
            bh[ks] = Bh[(ks * 8 + ct) * 64 + lane];
            bl[ks] = Bl[(ks * 8 + ct) * 64 + lane];
        }
        f32x4 acc = {0.f, 0.f, 0.f, 0.f};
#pragma unroll
        for (int ks = 0; ks < 4; ++ks) {
            acc = __builtin_amdgcn_mfma_f32_16x16x32_bf16(ah[ks], bh[ks], acc, 0, 0, 0);
            acc = __builtin_amdgcn_mfma_f32_16x16x32_bf16(al[ks], bh[ks], acc, 0, 0, 0);
            acc = __builtin_amdgcn_mfma_f32_16x16x32_bf16(ah[ks], bl[ks], acc, 0, 0, 0);
        }
        int c = ct * 16 + (lane & 15);
#pragma unroll
        for (int i = 0; i < 4; ++i) {
            int r = rb + i;
            if (r < M) Hb[(size_t)r * D + c] = f2bf(dsc[i] * acc[i]);
        }
    }
}

__global__ __launch_bounds__(256) void gemm2_k(const unsigned short* __restrict__ XH,
                                               const unsigned short* __restrict__ XL,
                                               const short* __restrict__ BFh,
                                               const short* __restrict__ BFl,
                                               const float* __restrict__ dinv,
                                               unsigned short* __restrict__ Hb, int M) {
    __shared__ uint4 WH[2048];
    __shared__ uint4 WL[2048];
    {
        const uint4* gh = (const uint4*)BFh;
        const uint4* gl = (const uint4*)BFl;
        int t = threadIdx.x;
#pragma unroll
        for (int i = 0; i < 8; ++i) WH[t + i * 256] = gh[t + i * 256];
#pragma unroll
        for (int i = 0; i < 8; ++i) WL[t + i * 256] = gl[t + i * 256];
    }

    int lane = threadIdx.x & 63;
    int rowBase = blockIdx.x * 64 + (threadIdx.x >> 6) * 16;
    int arow = rowBase + (lane & 15);
    bool aval = arow < M;
    const unsigned short* xh = XH + (size_t)arow * D + (lane >> 4) * 8;
    const unsigned short* xl = XL + (size_t)arow * D + (lane >> 4) * 8;

    short8v ah[4], al[4];
#pragma unroll
    for (int ks = 0; ks < 4; ++ks) {
        short8v zh = {0,0,0,0,0,0,0,0};
        short8v zl = {0,0,0,0,0,0,0,0};
        if (aval) {
            zh = *(const short8v*)(xh + ks * 32);
            zl = *(const short8v*)(xl + ks * 32);
        }
        ah[ks] = zh;
        al[ks] = zl;
    }
    __syncthreads();
    mfma_phase_l(ah, al, WH, WL, dinv, Hb, M, rowBase, lane);
}

// fused: blocks [0,gb) run gemm layer-0 (register-B, no LDS); [gb,..) CSR fill.
__global__ __launch_bounds__(256) void fillgemm_k(const float* __restrict__ X,
                                                  const short* __restrict__ BFh,
                                                  const short* __restrict__ BFl,
                                                  const float* __restrict__ dinv,
                                                  unsigned short* __restrict__ Hb, int M, int gb,
                                                  const int* __restrict__ src,
                                                  const int* __restrict__ dst,
                                                  const unsigned short* __restrict__ rank,
                                                  const int* __restrict__ rp, int E,
                                                  unsigned short* __restrict__ ssrc) {
    if ((int)blockIdx.x < gb) {
        int lane = threadIdx.x & 63;
        int rowBase = blockIdx.x * 64 + (threadIdx.x >> 6) * 16;
        short8v ah[4], al[4];
        load_a_f32(X, M, rowBase, lane, ah, al);
        mfma_phase_g(ah, al, BFh, BFl, dinv, Hb, M, rowBase, lane);
    } else {
        int e = (blockIdx.x - gb) * blockDim.x + threadIdx.x;
        if (e < E) {
            int p = rp[dst[e]] + (int)rank[e];
            ssrc[p] = (unsigned short)src[e];
        }
    }
}

// ---------------- sparse aggregation (lean, occupancy-max — r15 best form) ---
// out[n] = b + dinv[n] * ( h'[n] + sum_e h'[ssrc[e]] ).
// Lanes 16x4: one uint4/lane -> 4 rows per VMEM instr; butterfly 16/32;
// lanes 0-15 epilogue. Self-term prefetched. Bound by the shared per-CU
// miss-concurrency limit (r8/r11/r16 falsified all per-wave ILP levers).
// mode 0: write split bf16 (XH/XL). mode 1: GELU + f32 OUT.

__device__ __forceinline__ float gelu_f(float x) {
    return 0.5f * x * (1.0f + erff(x * 0.70710678118654752f));
}

__global__ __launch_bounds__(256) void agg_k(const unsigned short* __restrict__ Hb,
                                             const int* __restrict__ rp,
                                             const unsigned short* __restrict__ ssrc,
                                             const float* __restrict__ dinv,
                                             const float* __restrict__ bias,
                                             float* __restrict__ outF,
                                             unsigned short* __restrict__ outH,
                                             unsigned short* __restrict__ outL,
                                             int N, int mode) {
    int node = blockIdx.x * 4 + (threadIdx.x >> 6);
    int lane = threadIdx.x & 63;
    if (node >= N) return;
    const uint4* __restrict__ hb4 = (const uint4*)Hb;
    int grp = lane >> 4;
    int sub = lane & 15;

    // prefetch self-term early (used only by lanes<16 after the butterfly)
    uint4 sv = make_uint4(0u, 0u, 0u, 0u);
    if (lane < 16) sv = hb4[(size_t)node * 16 + lane];

    float acc[8];
#pragma unroll
    for (int i = 0; i < 8; ++i) acc[i] = 0.f;

    int e0 = rp[node];
    int e1 = rp[node + 1];
    for (int base = e0; base < e1; base += 64) {
        int idxv = 0;
        if (base + lane < e1) idxv = (int)ssrc[base + lane];
        int cnt = e1 - base; if (cnt > 64) cnt = 64;
        for (int c = 0; c < cnt; c += 16) {
            uint4 v[4];
#pragma unroll
            for (int j = 0; j < 4; ++j) {
                int row = __shfl(idxv, c + 4 * j + grp);
                v[j] = hb4[(size_t)row * 16 + sub];
            }
#pragma unroll
            for (int j = 0; j < 4; ++j) {
                bool ok = (base + c + 4 * j + grp) < e1;
                unsigned int w;
                w = ok ? v[j].x : 0u;
                acc[0] += __uint_as_float(w << 16); acc[1] += __uint_as_float(w & 0xFFFF0000u);
                w = ok ? v[j].y : 0u;
                acc[2] += __uint_as_float(w << 16); acc[3] += __uint_as_float(w & 0xFFFF0000u);
                w = ok ? v[j].z : 0u;
                acc[4] += __uint_as_float(w << 16); acc[5] += __uint_as_float(w & 0xFFFF0000u);
                w = ok ? v[j].w : 0u;
                acc[6] += __uint_as_float(w << 16); acc[7] += __uint_as_float(w & 0xFFFF0000u);
            }
        }
    }
#pragma unroll
    for (int i = 0; i < 8; ++i) {
        acc[i] += __shfl_xor(acc[i], 16);
        acc[i] += __shfl_xor(acc[i], 32);
    }
    if (lane < 16) {
        acc[0] += __uint_as_float(sv.x << 16); acc[1] += __uint_as_float(sv.x & 0xFFFF0000u);
        acc[2] += __uint_as_float(sv.y << 16); acc[3] += __uint_as_float(sv.y & 0xFFFF0000u);
        acc[4] += __uint_as_float(sv.z << 16); acc[5] += __uint_as_float(sv.z & 0xFFFF0000u);
        acc[6] += __uint_as_float(sv.w << 16); acc[7] += __uint_as_float(sv.w & 0xFFFF0000u);
        float dn = dinv[node];
        float4 b0 = ((const float4*)bias)[lane * 2];
        float4 b1 = ((const float4*)bias)[lane * 2 + 1];
        float r[8];
        r[0] = dn * acc[0] + b0.x; r[1] = dn * acc[1] + b0.y;
        r[2] = dn * acc[2] + b0.z; r[3] = dn * acc[3] + b0.w;
        r[4] = dn * acc[4] + b1.x; r[5] = dn * acc[5] + b1.y;
        r[6] = dn * acc[6] + b1.z; r[7] = dn * acc[7] + b1.w;
        if (mode) {
#pragma unroll
            for (int i = 0; i < 8; ++i) r[i] = gelu_f(r[i]);
            float4 o0 = make_float4(r[0], r[1], r[2], r[3]);
            float4 o1 = make_float4(r[4], r[5], r[6], r[7]);
            ((float4*)outF)[(size_t)node * 32 + lane * 2]     = o0;
            ((float4*)outF)[(size_t)node * 32 + lane * 2 + 1] = o1;
        } else {
            unsigned short h[8], lo[8];
#pragma unroll
            for (int i = 0; i < 8; ++i) {
                h[i]  = f2bf(r[i]);
                lo[i] = f2bf(r[i] - bf2f(h[i]));
            }
            uint4 ph, pl;
            ph.x = (unsigned int)h[0]  | ((unsigned int)h[1] << 16);
            ph.y = (unsigned int)h[2]  | ((unsigned int)h[3] << 16);
            ph.z = (unsigned int)h[4]  | ((unsigned int)h[5] << 16);
            ph.w = (unsigned int)h[6]  | ((unsigned int)h[7] << 16);
            pl.x = (unsigned int)lo[0] | ((unsigned int)lo[1] << 16);
            pl.y = (unsigned int)lo[2] | ((unsigned int)lo[3] << 16);
            pl.z = (unsigned int)lo[4] | ((unsigned int)lo[5] << 16);
            pl.w = (unsigned int)lo[6] | ((unsigned int)lo[7] << 16);
            ((uint4*)outH)[(size_t)node * 16 + lane] = ph;
            ((uint4*)outL)[(size_t)node * 16 + lane] = pl;
        }
    }
}

// ---------------- launch ----------------

extern "C" void kernel_launch(void* const* d_in, const int* in_sizes, int n_in,
                              void* d_out, int out_size, void* d_ws, size_t ws_size,
                              hipStream_t stream) {
    const float* X  = (const float*)d_in[0];
    const int*   EI = (const int*)d_in[1];
    const float* Wp = (const float*)d_in[2];
    const float* bp = (const float*)d_in[3];
    float* OUT = (float*)d_out;

    int N = in_sizes[0] / D;
    int E = in_sizes[1] / 2;
    int L = in_sizes[3] / D;   // 3
    const int* src = EI;
    const int* dst = EI + E;

    char* w = (char*)d_ws;
    auto alloc = [&](size_t bytes) {
        char* p = w;
        w += (bytes + 255) & ~(size_t)255;
        return p;
    };
    unsigned short* HB  = (unsigned short*)alloc((size_t)(N + 64) * D * sizeof(unsigned short));
    unsigned short* XH  = (unsigned short*)alloc((size_t)(N + 64) * D * sizeof(unsigned short));
    unsigned short* XL  = (unsigned short*)alloc((size_t)(N + 64) * D * sizeof(unsigned short));
    float* DINV = (float*)alloc((size_t)N * sizeof(float));
    int*   RP   = (int*)alloc((size_t)(N + 1) * sizeof(int));
    int*   CNT  = (int*)alloc((size_t)N * sizeof(int));
    int*   BSUM = (int*)alloc(4096 * sizeof(int));
    unsigned short* RANK = (unsigned short*)alloc((size_t)E * sizeof(unsigned short));
    unsigned short* SSRC = (unsigned short*)alloc(((size_t)E + 64) * sizeof(unsigned short));
    short* BFH  = (short*)alloc((size_t)L * D * D * sizeof(short));
    short* BFL  = (short*)alloc((size_t)L * D * D * sizeof(short));
    (void)ws_size; (void)n_in; (void)out_size;

    int wtot = L * D * D;
    int pb = ((N > wtot ? N : wtot) + 255) / 256;
    prep_k<<<pb, 256, 0, stream>>>(Wp, BFH, BFL, wtot, CNT, N);

    int eb = (E + 255) / 256;
    rank_k<<<eb, 256, 0, stream>>>(dst, E, CNT, RANK);
    int nb = (N + 1023) / 1024;
    scan_a<<<nb, 1024, 0, stream>>>(CNT, N, RP, BSUM);
    scan_c<<<(N + 255) / 256, 256, 0, stream>>>(CNT, RP, BSUM, DINV, N, E);

    int gb = (N + 63) / 64;
    fillgemm_k<<<gb + eb, 256, 0, stream>>>(X, BFH, BFL, DINV, HB, N, gb,
                                            src, dst, RANK, RP, E, SSRC);

    int ab = (N + 3) / 4;
    agg_k<<<ab, 256, 0, stream>>>(HB, RP, SSRC, DINV, bp, nullptr, XH, XL, N, 0);
    gemm2_k<<<gb, 256, 0, stream>>>(XH, XL, BFH + (size_t)1 * D * D, BFL + (size_t)1 * D * D,
                                    DINV, HB, N);
    agg_k<<<ab, 256, 0, stream>>>(HB, RP, SSRC, DINV, bp + D, nullptr, XH, XL, N, 0);
    gemm2_k<<<gb, 256, 0, stream>>>(XH, XL, BFH + (size_t)2 * D * D, BFL + (size_t)2 * D * D,
                                    DINV, HB, N);
    agg_k<<<ab, 256, 0, stream>>>(HB, RP, SSRC, DINV, bp + 2 * D, OUT, nullptr, nullptr, N, 1);
}